// Round 4
// baseline (311.229 us; speedup 1.0000x reference)
//
#include <hip/hip_runtime.h>

#define E 2048
#define F 4
#define S_OUT 4096

// ws layout: v[F*E] floats at 0, row[E] floats after.
// Math: softmax over a size-1 axis == 1, so ctx[s] == v for all s.
//   v_f  = h_last @ Wc_f[:, E:] + bc_f[E:]
//   row  = sum_f v_f @ Wp_f + sum_f bp_f
//   out[s, :] = row  for all 4096 s.
//
// SELF-TIMING PROBE (round 4): pipeline is run TWICE (idempotent — k_init
// re-seeds before the second accumulate pass). dur_us delta vs round 3
// measures my kernels' aggregate time inside the fixed harness overhead.

// K0: v[f][e] = bc[f][E+e]; row[o] = sum_f bp[f][o]  (ws is poisoned -> must seed)
__global__ void k_init(const float* __restrict__ bc, const float* __restrict__ bp,
                       float* __restrict__ v, float* __restrict__ row) {
    int idx = blockIdx.x * blockDim.x + threadIdx.x;
    if (idx < F * E) {
        int f = idx >> 11, e = idx & (E - 1);
        v[idx] = bc[f * 2 * E + E + e];
    } else if (idx < F * E + E) {
        int o = idx - F * E;
        float s = 0.f;
#pragma unroll
        for (int f = 0; f < F; ++f) s += bp[f * E + o];
        row[o] = s;
    }
}

// K1: v[f][e] += sum_i h_last[i] * Wc[f][i][E+e]
// grid: (E/32 i-splits, E/256, F) = 2048 blocks, 32 iters/thread, unroll 8.
__global__ void k_v(const float* __restrict__ h_last, const float* __restrict__ Wc,
                    float* __restrict__ v) {
    const int e  = blockIdx.y * 256 + threadIdx.x;
    const int f  = blockIdx.z;
    const int i0 = blockIdx.x * 32;
    const float* w = Wc + (size_t)f * E * 2 * E + (size_t)i0 * 2 * E + E + e;
    float acc = 0.f;
#pragma unroll 8
    for (int i = 0; i < 32; ++i) {
        acc = fmaf(h_last[i0 + i], w[(size_t)i * (2 * E)], acc);
    }
    atomicAdd(&v[f * E + e], acc);
}

// K2: row[o] += sum_{fe} v[fe] * Wp[fe][o]   (Wp flat: [F*E][E])
// grid: (F*E/128 fe-splits, E/256) = 512 blocks, 128 iters/thread, unroll 8.
__global__ void k_row(const float* __restrict__ v, const float* __restrict__ Wp,
                      float* __restrict__ row) {
    const int o   = blockIdx.y * 256 + threadIdx.x;
    const int fe0 = blockIdx.x * 128;
    const float* w = Wp + (size_t)fe0 * E + o;
    float acc = 0.f;
#pragma unroll 8
    for (int r = 0; r < 128; ++r) {
        acc = fmaf(v[fe0 + r], w[(size_t)r * E], acc);
    }
    atomicAdd(&row[o], acc);
}

// K3: out[s][:] = row[:] for all s, float4 stores (write-bound, 33.5 MB)
__global__ void k_bcast(const float* __restrict__ row, float4* __restrict__ out) {
    int idx = blockIdx.x * blockDim.x + threadIdx.x;   // over S_OUT*E/4
    const float4* r4 = (const float4*)row;
    out[idx] = r4[idx & (E / 4 - 1)];
}

extern "C" void kernel_launch(void* const* d_in, const int* in_sizes, int n_in,
                              void* d_out, int out_size, void* d_ws, size_t ws_size,
                              hipStream_t stream) {
    const float* hs = (const float*)d_in[0];   // (1,128,E)
    const float* Wc = (const float*)d_in[4];   // (F,E,2E)
    const float* bc = (const float*)d_in[5];   // (F,2E)
    const float* Wp = (const float*)d_in[6];   // (F,E,E)
    const float* bp = (const float*)d_in[7];   // (F,E)
    float* out = (float*)d_out;                // (1,S_OUT,E) f32

    float* v   = (float*)d_ws;                 // F*E floats
    float* row = v + F * E;                    // E floats

    const float* h_last = hs + 127 * E;        // hidden_states[0, -1, :]

    // Pass 1
    k_init<<<(F * E + E + 255) / 256, 256, 0, stream>>>(bc, bp, v, row);
    k_v<<<dim3(E / 32, E / 256, F), 256, 0, stream>>>(h_last, Wc, v);
    k_row<<<dim3(F * E / 128, E / 256), 256, 0, stream>>>(v, Wp, row);
    k_bcast<<<(S_OUT * E / 4) / 256, 256, 0, stream>>>(row, (float4*)out);
    // Pass 2 (identical — probe to measure own aggregate time via dur_us delta)
    k_init<<<(F * E + E + 255) / 256, 256, 0, stream>>>(bc, bp, v, row);
    k_v<<<dim3(E / 32, E / 256, F), 256, 0, stream>>>(h_last, Wc, v);
    k_row<<<dim3(F * E / 128, E / 256), 256, 0, stream>>>(v, Wp, row);
    k_bcast<<<(S_OUT * E / 4) / 256, 256, 0, stream>>>(row, (float4*)out);
}

// Round 5
// 280.385 us; speedup vs baseline: 1.1100x; 1.1100x over previous
//
#include <hip/hip_runtime.h>

#define E 2048
#define F 4
#define S_OUT 4096

// ws layout: v[F*E] floats at 0, row[E] floats after.
// Math: softmax over a size-1 axis == 1, so ctx[s] == v for all s.
//   v_f  = h_last @ Wc_f[:, E:] + bc_f[E:]
//   row  = sum_f v_f @ Wp_f + sum_f bp_f
//   out[s, :] = row  for all 4096 s.
//
// Round-4 probe measured this pipeline's aggregate cost at ~30 µs
// (byte floor ~26 µs) inside a 281 µs harness-dominated dur_us.

// K0: v[f][e] = bc[f][E+e]; row[o] = sum_f bp[f][o]  (ws is poisoned -> must seed)
__global__ void k_init(const float* __restrict__ bc, const float* __restrict__ bp,
                       float* __restrict__ v, float* __restrict__ row) {
    int idx = blockIdx.x * blockDim.x + threadIdx.x;
    if (idx < F * E) {
        int f = idx >> 11, e = idx & (E - 1);
        v[idx] = bc[f * 2 * E + E + e];
    } else if (idx < F * E + E) {
        int o = idx - F * E;
        float s = 0.f;
#pragma unroll
        for (int f = 0; f < F; ++f) s += bp[f * E + o];
        row[o] = s;
    }
}

// K1: v[f][e] += sum_i h_last[i] * Wc[f][i][E+e]
// grid: (E/32 i-splits, E/256, F) = 2048 blocks, 32 iters/thread, unroll 8.
__global__ void k_v(const float* __restrict__ h_last, const float* __restrict__ Wc,
                    float* __restrict__ v) {
    const int e  = blockIdx.y * 256 + threadIdx.x;
    const int f  = blockIdx.z;
    const int i0 = blockIdx.x * 32;
    const float* w = Wc + (size_t)f * E * 2 * E + (size_t)i0 * 2 * E + E + e;
    float acc = 0.f;
#pragma unroll 8
    for (int i = 0; i < 32; ++i) {
        acc = fmaf(h_last[i0 + i], w[(size_t)i * (2 * E)], acc);
    }
    atomicAdd(&v[f * E + e], acc);
}

// K2: row[o] += sum_{fe} v[fe] * Wp[fe][o]   (Wp flat: [F*E][E])
// grid: (F*E/128 fe-splits, E/256) = 512 blocks, 128 iters/thread, unroll 8.
__global__ void k_row(const float* __restrict__ v, const float* __restrict__ Wp,
                      float* __restrict__ row) {
    const int o   = blockIdx.y * 256 + threadIdx.x;
    const int fe0 = blockIdx.x * 128;
    const float* w = Wp + (size_t)fe0 * E + o;
    float acc = 0.f;
#pragma unroll 8
    for (int r = 0; r < 128; ++r) {
        acc = fmaf(v[fe0 + r], w[(size_t)r * E], acc);
    }
    atomicAdd(&row[o], acc);
}

// K3: out[s][:] = row[:] for all s, float4 stores (write-bound, 33.5 MB)
__global__ void k_bcast(const float* __restrict__ row, float4* __restrict__ out) {
    int idx = blockIdx.x * blockDim.x + threadIdx.x;   // over S_OUT*E/4
    const float4* r4 = (const float4*)row;
    out[idx] = r4[idx & (E / 4 - 1)];
}

extern "C" void kernel_launch(void* const* d_in, const int* in_sizes, int n_in,
                              void* d_out, int out_size, void* d_ws, size_t ws_size,
                              hipStream_t stream) {
    const float* hs = (const float*)d_in[0];   // (1,128,E)
    const float* Wc = (const float*)d_in[4];   // (F,E,2E)
    const float* bc = (const float*)d_in[5];   // (F,2E)
    const float* Wp = (const float*)d_in[6];   // (F,E,E)
    const float* bp = (const float*)d_in[7];   // (F,E)
    float* out = (float*)d_out;                // (1,S_OUT,E) f32

    float* v   = (float*)d_ws;                 // F*E floats
    float* row = v + F * E;                    // E floats

    const float* h_last = hs + 127 * E;        // hidden_states[0, -1, :]

    k_init<<<(F * E + E + 255) / 256, 256, 0, stream>>>(bc, bp, v, row);
    k_v<<<dim3(E / 32, E / 256, F), 256, 0, stream>>>(h_last, Wc, v);
    k_row<<<dim3(F * E / 128, E / 256), 256, 0, stream>>>(v, Wp, row);
    k_bcast<<<(S_OUT * E / 4) / 256, 256, 0, stream>>>(row, (float4*)out);
}